// Round 2
// baseline (143.744 us; speedup 1.0000x reference)
//
#include <hip/hip_runtime.h>
#include <hip/hip_bf16.h>

#define NF 200
#define ND 32
#define NK 4
#define NH1 32
#define NH2 16
#define BN_EPS 1e-3f
#define WS_PER_ROW 132   // 4 experts * 32 ctx-sums + 4 softmax denoms

// ---------------------------------------------------------------------------
// Kernel A: pure streaming pass over x. One wave per row, no LDS, no barriers.
// Lane = fg*8 + dl: fg = f-row within 8-row group, dl = float4 d-slice.
// 25 f-groups, processed as 5 batches of 5 (5 loads in flight per wave).
// Writes raw (un-normalized) context sums + softmax denominators to ws.
// ---------------------------------------------------------------------------
__global__ __launch_bounds__(256) void mvke_stream(
    const float* __restrict__ x, const float* __restrict__ vk,
    float* __restrict__ ws, int nrows)
{
  const int tid  = threadIdx.x;
  const int wave = tid >> 6;
  const int lane = tid & 63;
  const int fg   = lane >> 3;
  const int dl   = lane & 7;
  const int row  = blockIdx.x * 4 + wave;
  if (row >= nrows) return;          // wave-uniform exit; no sync in this kernel

  // vk transposed into registers: vkt[k][j] = vk[(4*dl+j), k]
  float vkt[NK][4];
  #pragma unroll
  for (int j = 0; j < 4; ++j) {
    const float4 vv = *(const float4*)(vk + (4*dl + j) * NK);
    vkt[0][j] = vv.x; vkt[1][j] = vv.y; vkt[2][j] = vv.z; vkt[3][j] = vv.w;
  }

  const float* xrow = x + (size_t)row * (NF*ND);
  const int laneoff = fg*ND + dl*4;

  float cx[NK], cy[NK], cz[NK], cw[NK], ls[NK];
  #pragma unroll
  for (int k = 0; k < NK; ++k) { cx[k]=cy[k]=cz[k]=cw[k]=ls[k]=0.f; }

  for (int it = 0; it < 5; ++it) {
    float4 xa[5];
    #pragma unroll
    for (int j = 0; j < 5; ++j)
      xa[j] = *(const float4*)(xrow + (it*5 + j)*(8*ND) + laneoff);
    #pragma unroll
    for (int j = 0; j < 5; ++j) {
      #pragma unroll
      for (int k = 0; k < NK; ++k) {
        float t = xa[j].x*vkt[k][0] + xa[j].y*vkt[k][1]
                + xa[j].z*vkt[k][2] + xa[j].w*vkt[k][3];
        t += __shfl_xor(t, 1);
        t += __shfl_xor(t, 2);
        t += __shfl_xor(t, 4);       // all 8 dl-lanes of this fg now hold s_k(f)
        const float p = __expf(t);   // |s| small (x~N(0,1), vk~0.1N) -> safe
        ls[k] += p;
        cx[k] = fmaf(p, xa[j].x, cx[k]);
        cy[k] = fmaf(p, xa[j].y, cy[k]);
        cz[k] = fmaf(p, xa[j].z, cz[k]);
        cw[k] = fmaf(p, xa[j].w, cw[k]);
      }
    }
  }

  // combine the 8 f-groups (masks 8,16,32)
  #pragma unroll
  for (int k = 0; k < NK; ++k) {
    #pragma unroll
    for (int m = 8; m <= 32; m <<= 1) {
      ls[k] += __shfl_xor(ls[k], m);
      cx[k] += __shfl_xor(cx[k], m);
      cy[k] += __shfl_xor(cy[k], m);
      cz[k] += __shfl_xor(cz[k], m);
      cw[k] += __shfl_xor(cw[k], m);
    }
  }

  float* wr = ws + (size_t)row * WS_PER_ROW;
  if (fg == 0) {
    #pragma unroll
    for (int k = 0; k < NK; ++k) {
      float4 v; v.x = cx[k]; v.y = cy[k]; v.z = cz[k]; v.w = cw[k];
      *(float4*)(wr + k*ND + dl*4) = v;
    }
    if (dl == 0) {
      float4 l4; l4.x = ls[0]; l4.y = ls[1]; l4.z = ls[2]; l4.w = ls[3];
      *(float4*)(wr + NK*ND) = l4;
    }
  }
}

// ---------------------------------------------------------------------------
// Kernel B: finish. Reads ws (raw ctx sums + denoms), normalizes, runs the
// two per-expert tower stages with folded BN, gates by tag softmax.
// One wave per row, 4 waves/block. Tiny (~12 MB traffic).
// ---------------------------------------------------------------------------
__global__ __launch_bounds__(256) void mvke_finish(
    const float* __restrict__ ws, const float* __restrict__ tag,
    const float* __restrict__ vk,
    const float* __restrict__ W1, const float* __restrict__ b1,
    const float* __restrict__ g1, const float* __restrict__ be1,
    const float* __restrict__ m1, const float* __restrict__ v1,
    const float* __restrict__ W2, const float* __restrict__ b2,
    const float* __restrict__ g2, const float* __restrict__ be2,
    const float* __restrict__ m2, const float* __restrict__ v2,
    float* __restrict__ out, int nrows)
{
  __shared__ float w1s[NK*ND*NH1];    // 16 KB
  __shared__ float w2s[NK*NH1*NH2];   //  8 KB
  __shared__ float a1s[NK*NH1], c1s[NK*NH1];
  __shared__ float a2s[NK*NH2], c2s[NK*NH2];
  __shared__ float ctx_s[4][NK*ND];
  __shared__ float h1_s[4][NK*NH1];

  const int tid = threadIdx.x;
  for (int i = tid; i < NK*ND*NH1; i += 256) w1s[i] = W1[i];
  for (int i = tid; i < NK*NH1*NH2; i += 256) w2s[i] = W2[i];
  if (tid < NK*NH1) {
    const float a = g1[tid] * rsqrtf(v1[tid] + BN_EPS);
    a1s[tid] = a;
    c1s[tid] = (b1[tid] - m1[tid]) * a + be1[tid];
  } else if (tid >= 128 && tid < 128 + NK*NH2) {
    const int t = tid - 128;
    const float a = g2[t] * rsqrtf(v2[t] + BN_EPS);
    a2s[t] = a;
    c2s[t] = (b2[t] - m2[t]) * a + be2[t];
  }

  const int wave = tid >> 6;
  const int lane = tid & 63;
  const int row  = blockIdx.x * 4 + wave;
  const bool live = (row < nrows);
  const float scale = 0.17677669529663687f;  // 1/sqrt(32)

  const float* wr = ws + (size_t)(live ? row : 0) * WS_PER_ROW;
  {
    const float  r0 = wr[lane];
    const float  r1 = wr[64 + lane];
    const float4 l4 = *(const float4*)(wr + NK*ND);
    const float inv0 = scale / ((lane      >> 5) == 0 ? l4.x : l4.y);
    const float inv1 = scale / (((64+lane) >> 5) == 2 ? l4.z : l4.w);
    ctx_s[wave][lane]      = r0 * inv0;
    ctx_s[wave][64 + lane] = r1 * inv1;
  }
  __syncthreads();   // covers weight preload + ctx_s writes

  // tower 1: 128 outputs, 2 per lane
  #pragma unroll
  for (int rep = 0; rep < 2; ++rep) {
    const int o = lane + rep*64;
    const int k = o >> 5, h = o & 31;
    const float* wp = &w1s[k*(ND*NH1) + h];
    const float* cp = &ctx_s[wave][k*ND];
    float acc = 0.f;
    #pragma unroll
    for (int d = 0; d < ND; ++d) acc = fmaf(cp[d], wp[d*NH1], acc);
    h1_s[wave][o] = fmaxf(fmaf(acc, a1s[o], c1s[o]), 0.f);
  }
  __syncthreads();

  // tower 2 + gate + output
  {
    const int k3 = lane >> 4, j3 = lane & 15;
    const float* wp = &w2s[k3*(NH1*NH2) + j3];
    const float* hp = &h1_s[wave][k3*NH1];
    float acc = 0.f;
    #pragma unroll
    for (int h = 0; h < NH1; ++h) acc = fmaf(hp[h], wp[h*NH2], acc);
    const int o = k3*NH2 + j3;
    const float h2v = fmaxf(fmaf(acc, a2s[o], c2s[o]), 0.f);

    const float* tp = tag + (size_t)(live ? row : 0) * ND;
    float gs0=0.f, gs1=0.f, gs2=0.f, gs3=0.f;
    #pragma unroll
    for (int d = 0; d < ND; ++d) {
      const float t = tp[d];
      const float4 vv = *(const float4*)(vk + d*NK);
      gs0 = fmaf(t, vv.x, gs0);
      gs1 = fmaf(t, vv.y, gs1);
      gs2 = fmaf(t, vv.z, gs2);
      gs3 = fmaf(t, vv.w, gs3);
    }
    gs0 *= scale; gs1 *= scale; gs2 *= scale; gs3 *= scale;
    const float mx = fmaxf(fmaxf(gs0, gs1), fmaxf(gs2, gs3));
    const float e0 = __expf(gs0-mx), e1 = __expf(gs1-mx),
                e2 = __expf(gs2-mx), e3 = __expf(gs3-mx);
    const float esum = e0 + e1 + e2 + e3;
    const float ek = (k3 == 0) ? e0 : (k3 == 1) ? e1 : (k3 == 2) ? e2 : e3;

    float val = (ek / esum) * h2v;
    val += __shfl_xor(val, 16);
    val += __shfl_xor(val, 32);
    if (live && lane < NH2) out[(size_t)row*NH2 + lane] = val;
  }
}

// ---------------------------------------------------------------------------
// Fallback: the round-0 fully-fused kernel (used only if ws is too small).
// ---------------------------------------------------------------------------
__global__ __launch_bounds__(256) void mvke_fused(
    const float* __restrict__ x, const float* __restrict__ tag,
    const float* __restrict__ vk,
    const float* __restrict__ W1, const float* __restrict__ b1,
    const float* __restrict__ g1, const float* __restrict__ be1,
    const float* __restrict__ m1, const float* __restrict__ v1,
    const float* __restrict__ W2, const float* __restrict__ b2,
    const float* __restrict__ g2, const float* __restrict__ be2,
    const float* __restrict__ m2, const float* __restrict__ v2,
    float* __restrict__ out, int nrows)
{
  __shared__ float w1s[NK*ND*NH1];
  __shared__ float w2s[NK*NH1*NH2];
  __shared__ float a1s[NK*NH1], c1s[NK*NH1];
  __shared__ float a2s[NK*NH2], c2s[NK*NH2];
  __shared__ float ctx_s[4][NK*ND];
  __shared__ float h1_s[4][NK*NH1];

  const int tid = threadIdx.x;
  for (int i = tid; i < NK*ND*NH1; i += 256) w1s[i] = W1[i];
  for (int i = tid; i < NK*NH1*NH2; i += 256) w2s[i] = W2[i];
  if (tid < NK*NH1) {
    const float a = g1[tid] * rsqrtf(v1[tid] + BN_EPS);
    a1s[tid] = a;
    c1s[tid] = (b1[tid] - m1[tid]) * a + be1[tid];
  } else if (tid >= 128 && tid < 128 + NK*NH2) {
    const int t = tid - 128;
    const float a = g2[t] * rsqrtf(v2[t] + BN_EPS);
    a2s[t] = a;
    c2s[t] = (b2[t] - m2[t]) * a + be2[t];
  }

  const int wave = tid >> 6;
  const int lane = tid & 63;
  const int fg   = lane >> 3;
  const int dl   = lane & 7;
  const int row  = blockIdx.x * 4 + wave;
  const bool live = (row < nrows);

  float vkt[NK][4];
  #pragma unroll
  for (int j = 0; j < 4; ++j) {
    const float4 vv = *(const float4*)(vk + (4*dl + j) * NK);
    vkt[0][j] = vv.x; vkt[1][j] = vv.y; vkt[2][j] = vv.z; vkt[3][j] = vv.w;
  }

  const float* xrow = x + (size_t)(live ? row : 0) * (NF*ND);
  const int laneoff = fg*ND + dl*4;

  float cx[NK], cy[NK], cz[NK], cw[NK], ls[NK];
  #pragma unroll
  for (int k = 0; k < NK; ++k) { cx[k]=cy[k]=cz[k]=cw[k]=ls[k]=0.f; }

  for (int it = 0; it < NF/8; ++it) {
    const float4 xa = *(const float4*)(xrow + it*(8*ND) + laneoff);
    #pragma unroll
    for (int k = 0; k < NK; ++k) {
      float t = xa.x*vkt[k][0] + xa.y*vkt[k][1] + xa.z*vkt[k][2] + xa.w*vkt[k][3];
      t += __shfl_xor(t, 1);
      t += __shfl_xor(t, 2);
      t += __shfl_xor(t, 4);
      const float p = __expf(t);
      ls[k] += p;
      cx[k] = fmaf(p, xa.x, cx[k]);
      cy[k] = fmaf(p, xa.y, cy[k]);
      cz[k] = fmaf(p, xa.z, cz[k]);
      cw[k] = fmaf(p, xa.w, cw[k]);
    }
  }

  #pragma unroll
  for (int k = 0; k < NK; ++k) {
    #pragma unroll
    for (int m = 8; m <= 32; m <<= 1) {
      ls[k] += __shfl_xor(ls[k], m);
      cx[k] += __shfl_xor(cx[k], m);
      cy[k] += __shfl_xor(cy[k], m);
      cz[k] += __shfl_xor(cz[k], m);
      cw[k] += __shfl_xor(cw[k], m);
    }
  }

  const float scale = 0.17677669529663687f;
  if (fg == 0) {
    #pragma unroll
    for (int k = 0; k < NK; ++k) {
      const float inv = scale / ls[k];
      float* p = &ctx_s[wave][k*ND + dl*4];
      p[0] = cx[k]*inv; p[1] = cy[k]*inv; p[2] = cz[k]*inv; p[3] = cw[k]*inv;
    }
  }
  __syncthreads();

  #pragma unroll
  for (int rep = 0; rep < 2; ++rep) {
    const int o = lane + rep*64;
    const int k = o >> 5, h = o & 31;
    const float* wp = &w1s[k*(ND*NH1) + h];
    const float* cp = &ctx_s[wave][k*ND];
    float acc = 0.f;
    #pragma unroll
    for (int d = 0; d < ND; ++d) acc = fmaf(cp[d], wp[d*NH1], acc);
    h1_s[wave][o] = fmaxf(fmaf(acc, a1s[o], c1s[o]), 0.f);
  }
  __syncthreads();

  {
    const int k3 = lane >> 4, j3 = lane & 15;
    const float* wp = &w2s[k3*(NH1*NH2) + j3];
    const float* hp = &h1_s[wave][k3*NH1];
    float acc = 0.f;
    #pragma unroll
    for (int h = 0; h < NH1; ++h) acc = fmaf(hp[h], wp[h*NH2], acc);
    const int o = k3*NH2 + j3;
    const float h2v = fmaxf(fmaf(acc, a2s[o], c2s[o]), 0.f);

    const float* tp = tag + (size_t)(live ? row : 0) * ND;
    float gs0=0.f, gs1=0.f, gs2=0.f, gs3=0.f;
    #pragma unroll
    for (int d = 0; d < ND; ++d) {
      const float t = tp[d];
      const float4 vv = *(const float4*)(vk + d*NK);
      gs0 = fmaf(t, vv.x, gs0);
      gs1 = fmaf(t, vv.y, gs1);
      gs2 = fmaf(t, vv.z, gs2);
      gs3 = fmaf(t, vv.w, gs3);
    }
    gs0 *= scale; gs1 *= scale; gs2 *= scale; gs3 *= scale;
    const float mx = fmaxf(fmaxf(gs0, gs1), fmaxf(gs2, gs3));
    const float e0 = __expf(gs0-mx), e1 = __expf(gs1-mx),
                e2 = __expf(gs2-mx), e3 = __expf(gs3-mx);
    const float esum = e0 + e1 + e2 + e3;
    const float ek = (k3 == 0) ? e0 : (k3 == 1) ? e1 : (k3 == 2) ? e2 : e3;

    float val = (ek / esum) * h2v;
    val += __shfl_xor(val, 16);
    val += __shfl_xor(val, 32);
    if (live && lane < NH2) out[(size_t)row*NH2 + lane] = val;
  }
}

extern "C" void kernel_launch(void* const* d_in, const int* in_sizes, int n_in,
                              void* d_out, int out_size, void* d_ws, size_t ws_size,
                              hipStream_t stream) {
  const float* x   = (const float*)d_in[0];
  const float* tag = (const float*)d_in[1];
  const float* vk  = (const float*)d_in[2];
  const float* W1  = (const float*)d_in[3];
  const float* b1  = (const float*)d_in[4];
  const float* g1  = (const float*)d_in[5];
  const float* be1 = (const float*)d_in[6];
  const float* m1  = (const float*)d_in[7];
  const float* v1  = (const float*)d_in[8];
  const float* W2  = (const float*)d_in[9];
  const float* b2  = (const float*)d_in[10];
  const float* g2  = (const float*)d_in[11];
  const float* be2 = (const float*)d_in[12];
  const float* m2  = (const float*)d_in[13];
  const float* v2  = (const float*)d_in[14];
  float* out = (float*)d_out;

  const int nrows = in_sizes[1] / ND;          // B from tag_embedding
  const int nblocks = (nrows + 3) / 4;
  const size_t ws_need = (size_t)nrows * WS_PER_ROW * sizeof(float);

  if (ws_size >= ws_need) {
    mvke_stream<<<nblocks, 256, 0, stream>>>(x, vk, (float*)d_ws, nrows);
    mvke_finish<<<nblocks, 256, 0, stream>>>((const float*)d_ws, tag, vk,
                                             W1, b1, g1, be1, m1, v1,
                                             W2, b2, g2, be2, m2, v2, out, nrows);
  } else {
    mvke_fused<<<nblocks, 256, 0, stream>>>(x, tag, vk, W1, b1, g1, be1, m1, v1,
                                            W2, b2, g2, be2, m2, v2, out, nrows);
  }
}

// Round 3
// 111.496 us; speedup vs baseline: 1.2892x; 1.2892x over previous
//
#include <hip/hip_runtime.h>
#include <hip/hip_bf16.h>

#define NF 200
#define ND 32
#define NK 4
#define NH1 32
#define NH2 16
#define BN_EPS 1e-3f

// v + dpp_shuffled(v): all-VALU cross-lane add (no LDS pipe).
// CTRL: 0xB1 = quad_perm [1,0,3,2] (xor 1), 0x4E = quad_perm [2,3,0,1] (xor 2),
//       0x141 = row_half_mirror (xor-within-8 completing an 8-lane sum),
//       0x128 = row_ror:8 (== xor 8 within a 16-lane row).
template<int CTRL>
__device__ __forceinline__ float dpp_add(float v) {
  const int r = __builtin_amdgcn_update_dpp(0, __float_as_int(v), CTRL, 0xF, 0xF, true);
  return v + __int_as_float(r);
}

// One wave per batch row, 4 waves/block. Lane = fg*8 + dl:
//   fg in [0,8): f-row within the 8-row group of this iteration
//   dl in [0,8): float4 d-slice (d = 4*dl .. 4*dl+3)
// 25 iterations x 8 f-rows = F=200. Each wave-load is 1 KB contiguous.
// Score reduction over the 8 dl-lanes is pure-DPP (VALU), zero LDS ops
// in the main loop; online un-normalized softmax (|s| small, fp32-safe).
__global__ __launch_bounds__(256, 8) void mvke_fused(
    const float* __restrict__ x, const float* __restrict__ tag,
    const float* __restrict__ vk,
    const float* __restrict__ W1, const float* __restrict__ b1,
    const float* __restrict__ g1, const float* __restrict__ be1,
    const float* __restrict__ m1, const float* __restrict__ v1,
    const float* __restrict__ W2, const float* __restrict__ b2,
    const float* __restrict__ g2, const float* __restrict__ be2,
    const float* __restrict__ m2, const float* __restrict__ v2,
    float* __restrict__ out, int nrows)
{
  __shared__ float w1s[NK*ND*NH1];    // 16 KB
  __shared__ float w2s[NK*NH1*NH2];   //  8 KB
  __shared__ float a1s[NK*NH1], c1s[NK*NH1];
  __shared__ float a2s[NK*NH2], c2s[NK*NH2];
  __shared__ float ctx_s[4][NK*ND];
  __shared__ float h1_s[4][NK*NH1];

  const int tid = threadIdx.x;
  // block-wide preload of weights + folded BN params
  for (int i = tid; i < NK*ND*NH1; i += 256) w1s[i] = W1[i];
  for (int i = tid; i < NK*NH1*NH2; i += 256) w2s[i] = W2[i];
  if (tid < NK*NH1) {
    const float a = g1[tid] * rsqrtf(v1[tid] + BN_EPS);
    a1s[tid] = a;
    c1s[tid] = (b1[tid] - m1[tid]) * a + be1[tid];
  } else if (tid >= 128 && tid < 128 + NK*NH2) {
    const int t = tid - 128;
    const float a = g2[t] * rsqrtf(v2[t] + BN_EPS);
    a2s[t] = a;
    c2s[t] = (b2[t] - m2[t]) * a + be2[t];
  }

  const int wave = tid >> 6;
  const int lane = tid & 63;
  const int fg   = lane >> 3;
  const int dl   = lane & 7;
  const int row  = blockIdx.x * 4 + wave;
  const bool live = (row < nrows);

  // vk transposed into registers: vkt[k][j] = vk[(4*dl+j), k]
  float vkt[NK][4];
  #pragma unroll
  for (int j = 0; j < 4; ++j) {
    const float4 vv = *(const float4*)(vk + (4*dl + j) * NK);
    vkt[0][j] = vv.x; vkt[1][j] = vv.y; vkt[2][j] = vv.z; vkt[3][j] = vv.w;
  }

  const float* xrow = x + (size_t)(live ? row : 0) * (NF*ND);
  const int laneoff = fg*ND + dl*4;

  float cx[NK], cy[NK], cz[NK], cw[NK], ls[NK];
  #pragma unroll
  for (int k = 0; k < NK; ++k) { cx[k]=cy[k]=cz[k]=cw[k]=ls[k]=0.f; }

  // ---- stage 1: streaming pass; per-score reduce is 3 DPP adds (VALU) ----
  for (int it = 0; it < NF/8; ++it) {
    const float4 xa = *(const float4*)(xrow + it*(8*ND) + laneoff);
    #pragma unroll
    for (int k = 0; k < NK; ++k) {
      float t = xa.x*vkt[k][0] + xa.y*vkt[k][1] + xa.z*vkt[k][2] + xa.w*vkt[k][3];
      t = dpp_add<0xB1>(t);            // + lane^1
      t = dpp_add<0x4E>(t);            // + lane^2
      t = dpp_add<0x141>(t);           // + lane^4 (half-row mirror)
      const float p = __expf(t);       // |s| <= ~6, fp32-safe unnormalized
      ls[k] += p;
      cx[k] = fmaf(p, xa.x, cx[k]);
      cy[k] = fmaf(p, xa.y, cy[k]);
      cz[k] = fmaf(p, xa.z, cz[k]);
      cw[k] = fmaf(p, xa.w, cw[k]);
    }
  }

  // ---- tail: combine the 8 f-groups (mask 8 via DPP, 16/32 via shfl) ----
  #pragma unroll
  for (int k = 0; k < NK; ++k) {
    ls[k] = dpp_add<0x128>(ls[k]);
    cx[k] = dpp_add<0x128>(cx[k]);
    cy[k] = dpp_add<0x128>(cy[k]);
    cz[k] = dpp_add<0x128>(cz[k]);
    cw[k] = dpp_add<0x128>(cw[k]);
    #pragma unroll
    for (int m = 16; m <= 32; m <<= 1) {
      ls[k] += __shfl_xor(ls[k], m);
      cx[k] += __shfl_xor(cx[k], m);
      cy[k] += __shfl_xor(cy[k], m);
      cz[k] += __shfl_xor(cz[k], m);
      cw[k] += __shfl_xor(cw[k], m);
    }
  }

  const float scale = 0.17677669529663687f;  // 1/sqrt(32)
  if (fg == 0) {
    #pragma unroll
    for (int k = 0; k < NK; ++k) {
      const float inv = scale / ls[k];
      float* p = &ctx_s[wave][k*ND + dl*4];
      p[0] = cx[k]*inv; p[1] = cy[k]*inv; p[2] = cz[k]*inv; p[3] = cw[k]*inv;
    }
  }
  __syncthreads();   // covers weight preload + ctx_s writes

  // ---- stage 2: tower 1 (Dense -> BN -> relu), 128 outputs, 2 per lane ----
  #pragma unroll
  for (int rep = 0; rep < 2; ++rep) {
    const int o = lane + rep*64;
    const int k = o >> 5, h = o & 31;
    const float* wp = &w1s[k*(ND*NH1) + h];
    const float* cp = &ctx_s[wave][k*ND];
    float acc = 0.f;
    #pragma unroll
    for (int d = 0; d < ND; ++d) acc = fmaf(cp[d], wp[d*NH1], acc);
    h1_s[wave][o] = fmaxf(fmaf(acc, a1s[o], c1s[o]), 0.f);
  }
  __syncthreads();

  // ---- stage 3: tower 2 + gate + output ----
  {
    const int k3 = lane >> 4, j3 = lane & 15;
    const float* wp = &w2s[k3*(NH1*NH2) + j3];
    const float* hp = &h1_s[wave][k3*NH1];
    float acc = 0.f;
    #pragma unroll
    for (int h = 0; h < NH1; ++h) acc = fmaf(hp[h], wp[h*NH2], acc);
    const int o = k3*NH2 + j3;
    const float h2v = fmaxf(fmaf(acc, a2s[o], c2s[o]), 0.f);

    // gate from tag embedding (redundant per lane; tag row is L1-hot)
    const float* tp = tag + (size_t)(live ? row : 0) * ND;
    float gs0=0.f, gs1=0.f, gs2=0.f, gs3=0.f;
    #pragma unroll
    for (int d = 0; d < ND; ++d) {
      const float t = tp[d];
      const float4 vv = *(const float4*)(vk + d*NK);
      gs0 = fmaf(t, vv.x, gs0);
      gs1 = fmaf(t, vv.y, gs1);
      gs2 = fmaf(t, vv.z, gs2);
      gs3 = fmaf(t, vv.w, gs3);
    }
    gs0 *= scale; gs1 *= scale; gs2 *= scale; gs3 *= scale;
    const float mx = fmaxf(fmaxf(gs0, gs1), fmaxf(gs2, gs3));
    const float e0 = __expf(gs0-mx), e1 = __expf(gs1-mx),
                e2 = __expf(gs2-mx), e3 = __expf(gs3-mx);
    const float esum = e0 + e1 + e2 + e3;
    const float ek = (k3 == 0) ? e0 : (k3 == 1) ? e1 : (k3 == 2) ? e2 : e3;

    float val = (ek / esum) * h2v;
    val += __shfl_xor(val, 16);
    val += __shfl_xor(val, 32);        // sum over the 4 experts
    if (live && lane < NH2) out[(size_t)row*NH2 + lane] = val;
  }
}

extern "C" void kernel_launch(void* const* d_in, const int* in_sizes, int n_in,
                              void* d_out, int out_size, void* d_ws, size_t ws_size,
                              hipStream_t stream) {
  const float* x   = (const float*)d_in[0];
  const float* tag = (const float*)d_in[1];
  const float* vk  = (const float*)d_in[2];
  const float* W1  = (const float*)d_in[3];
  const float* b1  = (const float*)d_in[4];
  const float* g1  = (const float*)d_in[5];
  const float* be1 = (const float*)d_in[6];
  const float* m1  = (const float*)d_in[7];
  const float* v1  = (const float*)d_in[8];
  const float* W2  = (const float*)d_in[9];
  const float* b2  = (const float*)d_in[10];
  const float* g2  = (const float*)d_in[11];
  const float* be2 = (const float*)d_in[12];
  const float* m2  = (const float*)d_in[13];
  const float* v2  = (const float*)d_in[14];
  float* out = (float*)d_out;

  const int nrows = in_sizes[1] / ND;          // B from tag_embedding
  const int nblocks = (nrows + 3) / 4;         // 4 waves/block, 1 row/wave
  mvke_fused<<<nblocks, 256, 0, stream>>>(x, tag, vk, W1, b1, g1, be1, m1, v1,
                                          W2, b2, g2, be2, m2, v2, out, nrows);
}

// Round 4
// 108.028 us; speedup vs baseline: 1.3306x; 1.0321x over previous
//
#include <hip/hip_runtime.h>
#include <hip/hip_bf16.h>

#define NF 200
#define ND 32
#define NK 4
#define NH1 32
#define NH2 16
#define BN_EPS 1e-3f

// v + dpp_shuffled(v): all-VALU cross-lane add (no LDS pipe).
// CTRL: 0xB1 = quad_perm [1,0,3,2] (xor 1), 0x4E = quad_perm [2,3,0,1] (xor 2),
//       0x141 = row_half_mirror (xor 4 within 8), 0x128 = row_ror:8 (xor 8 in 16).
template<int CTRL>
__device__ __forceinline__ float dpp_add(float v) {
  const int r = __builtin_amdgcn_update_dpp(0, __float_as_int(v), CTRL, 0xF, 0xF, true);
  return v + __int_as_float(r);
}

// One wave per batch row, 4 waves/block, 4 KB LDS/block -> 8 blocks/CU
// (32 waves/CU). Weights/BN params read straight from global (L2-resident,
// coalesced). x stream uses explicit 2-deep prefetch: 2 KB/wave in flight.
__global__ __launch_bounds__(256, 8) void mvke_fused(
    const float* __restrict__ x, const float* __restrict__ tag,
    const float* __restrict__ vk,
    const float* __restrict__ W1, const float* __restrict__ b1,
    const float* __restrict__ g1, const float* __restrict__ be1,
    const float* __restrict__ m1, const float* __restrict__ v1,
    const float* __restrict__ W2, const float* __restrict__ b2,
    const float* __restrict__ g2, const float* __restrict__ be2,
    const float* __restrict__ m2, const float* __restrict__ v2,
    float* __restrict__ out, int nrows)
{
  __shared__ float ctx_s[4][NK*ND];   // per-wave pooled context   (2 KB)
  __shared__ float h1_s[4][NK*NH1];   // per-wave tower-1 output   (2 KB)

  const int tid  = threadIdx.x;
  const int wave = tid >> 6;
  const int lane = tid & 63;
  const int fg   = lane >> 3;
  const int dl   = lane & 7;
  const int row  = blockIdx.x * 4 + wave;
  const bool live = (row < nrows);

  // vk transposed into registers: vkt[k][j] = vk[(4*dl+j), k]
  float vkt[NK][4];
  #pragma unroll
  for (int j = 0; j < 4; ++j) {
    const float4 vv = *(const float4*)(vk + (4*dl + j) * NK);
    vkt[0][j] = vv.x; vkt[1][j] = vv.y; vkt[2][j] = vv.z; vkt[3][j] = vv.w;
  }

  const float* xrow = x + (size_t)(live ? row : 0) * (NF*ND);
  const int laneoff = fg*ND + dl*4;

  float cx[NK], cy[NK], cz[NK], cw[NK], ls[NK];
  #pragma unroll
  for (int k = 0; k < NK; ++k) { cx[k]=cy[k]=cz[k]=cw[k]=ls[k]=0.f; }

  // ---- stage 1: streaming pass, 2-deep prefetch, DPP-only reductions ----
  float4 xa = *(const float4*)(xrow + laneoff);
  for (int it = 0; it < NF/8; ++it) {
    float4 xn;
    if (it + 1 < NF/8)
      xn = *(const float4*)(xrow + (it+1)*(8*ND) + laneoff);
    #pragma unroll
    for (int k = 0; k < NK; ++k) {
      float t = xa.x*vkt[k][0] + xa.y*vkt[k][1] + xa.z*vkt[k][2] + xa.w*vkt[k][3];
      t = dpp_add<0xB1>(t);            // + lane^1
      t = dpp_add<0x4E>(t);            // + lane^2
      t = dpp_add<0x141>(t);           // + lane^4
      const float p = __expf(t);       // |s| small, un-normalized is fp32-safe
      ls[k] += p;
      cx[k] = fmaf(p, xa.x, cx[k]);
      cy[k] = fmaf(p, xa.y, cy[k]);
      cz[k] = fmaf(p, xa.z, cz[k]);
      cw[k] = fmaf(p, xa.w, cw[k]);
    }
    xa = xn;
  }

  // ---- tail: combine the 8 f-groups (mask 8 via DPP, 16/32 via shfl) ----
  #pragma unroll
  for (int k = 0; k < NK; ++k) {
    ls[k] = dpp_add<0x128>(ls[k]);
    cx[k] = dpp_add<0x128>(cx[k]);
    cy[k] = dpp_add<0x128>(cy[k]);
    cz[k] = dpp_add<0x128>(cz[k]);
    cw[k] = dpp_add<0x128>(cw[k]);
    #pragma unroll
    for (int m = 16; m <= 32; m <<= 1) {
      ls[k] += __shfl_xor(ls[k], m);
      cx[k] += __shfl_xor(cx[k], m);
      cy[k] += __shfl_xor(cy[k], m);
      cz[k] += __shfl_xor(cz[k], m);
      cw[k] += __shfl_xor(cw[k], m);
    }
  }

  const float scale = 0.17677669529663687f;  // 1/sqrt(32)
  if (fg == 0) {
    #pragma unroll
    for (int k = 0; k < NK; ++k) {
      const float inv = scale / ls[k];
      float* p = &ctx_s[wave][k*ND + dl*4];
      p[0] = cx[k]*inv; p[1] = cy[k]*inv; p[2] = cz[k]*inv; p[3] = cw[k]*inv;
    }
  }
  __syncthreads();

  // ---- stage 2: tower 1 (Dense -> BN -> relu); weights from global/L2 ----
  #pragma unroll
  for (int rep = 0; rep < 2; ++rep) {
    const int o = lane + rep*64;
    const int k = o >> 5, h = o & 31;
    const float* wp = W1 + k*(ND*NH1) + h;
    const float* cp = &ctx_s[wave][k*ND];
    float acc = 0.f;
    #pragma unroll
    for (int d = 0; d < ND; ++d) acc = fmaf(cp[d], wp[d*NH1], acc);
    const float a = g1[o] * rsqrtf(v1[o] + BN_EPS);
    const float c = fmaf(b1[o] - m1[o], a, be1[o]);
    h1_s[wave][o] = fmaxf(fmaf(acc, a, c), 0.f);
  }
  __syncthreads();

  // ---- stage 3: tower 2 + gate + output ----
  {
    const int k3 = lane >> 4, j3 = lane & 15;
    const float* wp = W2 + k3*(NH1*NH2) + j3;
    const float* hp = &h1_s[wave][k3*NH1];
    float acc = 0.f;
    #pragma unroll
    for (int h = 0; h < NH1; ++h) acc = fmaf(hp[h], wp[h*NH2], acc);
    const int o = k3*NH2 + j3;
    const float a2 = g2[o] * rsqrtf(v2[o] + BN_EPS);
    const float c2 = fmaf(b2[o] - m2[o], a2, be2[o]);
    const float h2v = fmaxf(fmaf(acc, a2, c2), 0.f);

    // gate from tag embedding (redundant per lane; tag row is L1-hot)
    const float* tp = tag + (size_t)(live ? row : 0) * ND;
    float gs0=0.f, gs1=0.f, gs2=0.f, gs3=0.f;
    #pragma unroll
    for (int d = 0; d < ND; ++d) {
      const float t = tp[d];
      const float4 vv = *(const float4*)(vk + d*NK);
      gs0 = fmaf(t, vv.x, gs0);
      gs1 = fmaf(t, vv.y, gs1);
      gs2 = fmaf(t, vv.z, gs2);
      gs3 = fmaf(t, vv.w, gs3);
    }
    gs0 *= scale; gs1 *= scale; gs2 *= scale; gs3 *= scale;
    const float mx = fmaxf(fmaxf(gs0, gs1), fmaxf(gs2, gs3));
    const float e0 = __expf(gs0-mx), e1 = __expf(gs1-mx),
                e2 = __expf(gs2-mx), e3 = __expf(gs3-mx);
    const float esum = e0 + e1 + e2 + e3;
    const float ek = (k3 == 0) ? e0 : (k3 == 1) ? e1 : (k3 == 2) ? e2 : e3;

    float val = (ek / esum) * h2v;
    val += __shfl_xor(val, 16);
    val += __shfl_xor(val, 32);        // sum over the 4 experts
    if (live && lane < NH2) out[(size_t)row*NH2 + lane] = val;
  }
}

extern "C" void kernel_launch(void* const* d_in, const int* in_sizes, int n_in,
                              void* d_out, int out_size, void* d_ws, size_t ws_size,
                              hipStream_t stream) {
  const float* x   = (const float*)d_in[0];
  const float* tag = (const float*)d_in[1];
  const float* vk  = (const float*)d_in[2];
  const float* W1  = (const float*)d_in[3];
  const float* b1  = (const float*)d_in[4];
  const float* g1  = (const float*)d_in[5];
  const float* be1 = (const float*)d_in[6];
  const float* m1  = (const float*)d_in[7];
  const float* v1  = (const float*)d_in[8];
  const float* W2  = (const float*)d_in[9];
  const float* b2  = (const float*)d_in[10];
  const float* g2  = (const float*)d_in[11];
  const float* be2 = (const float*)d_in[12];
  const float* m2  = (const float*)d_in[13];
  const float* v2  = (const float*)d_in[14];
  float* out = (float*)d_out;

  const int nrows = in_sizes[1] / ND;          // B from tag_embedding
  const int nblocks = (nrows + 3) / 4;         // 4 waves/block, 1 row/wave
  mvke_fused<<<nblocks, 256, 0, stream>>>(x, tag, vk, W1, b1, g1, be1, m1, v1,
                                          W2, b2, g2, be2, m2, v2, out, nrows);
}

// Round 5
// 101.437 us; speedup vs baseline: 1.4171x; 1.0650x over previous
//
#include <hip/hip_runtime.h>
#include <hip/hip_bf16.h>

#define NF 200
#define ND 32
#define NK 4
#define NH1 32
#define NH2 16
#define BN_EPS 1e-3f

// v + dpp_shuffled(v): all-VALU cross-lane add (no LDS pipe).
// CTRL: 0xB1 = quad_perm [1,0,3,2] (xor 1), 0x4E = quad_perm [2,3,0,1] (xor 2),
//       0x141 = row_half_mirror (xor 4 within 8), 0x128 = row_ror:8 (xor 8 in 16).
template<int CTRL>
__device__ __forceinline__ float dpp_add(float v) {
  const int r = __builtin_amdgcn_update_dpp(0, __float_as_int(v), CTRL, 0xF, 0xF, true);
  return v + __int_as_float(r);
}

// One wave per batch row, 4 waves/block, 4 KB LDS/block.
// Stream loop: 4-deep rotating register pipeline (compile-time buf indices),
// ~3.5-4 KB outstanding per wave => Little's-law headroom over HBM latency.
// All in-loop reductions are DPP (VALU); weights/BN read from global (L2-hot).
__global__ __launch_bounds__(256, 6) void mvke_fused(
    const float* __restrict__ x, const float* __restrict__ tag,
    const float* __restrict__ vk,
    const float* __restrict__ W1, const float* __restrict__ b1,
    const float* __restrict__ g1, const float* __restrict__ be1,
    const float* __restrict__ m1, const float* __restrict__ v1,
    const float* __restrict__ W2, const float* __restrict__ b2,
    const float* __restrict__ g2, const float* __restrict__ be2,
    const float* __restrict__ m2, const float* __restrict__ v2,
    float* __restrict__ out, int nrows)
{
  __shared__ float ctx_s[4][NK*ND];   // per-wave pooled context   (2 KB)
  __shared__ float h1_s[4][NK*NH1];   // per-wave tower-1 output   (2 KB)

  const int tid  = threadIdx.x;
  const int wave = tid >> 6;
  const int lane = tid & 63;
  const int fg   = lane >> 3;
  const int dl   = lane & 7;
  const int row  = blockIdx.x * 4 + wave;
  const bool live = (row < nrows);

  // vk transposed into registers: vkt[k][j] = vk[(4*dl+j), k]
  float vkt[NK][4];
  #pragma unroll
  for (int j = 0; j < 4; ++j) {
    const float4 vv = *(const float4*)(vk + (4*dl + j) * NK);
    vkt[0][j] = vv.x; vkt[1][j] = vv.y; vkt[2][j] = vv.z; vkt[3][j] = vv.w;
  }

  const float* xrow = x + (size_t)(live ? row : 0) * (NF*ND);
  const int laneoff = fg*ND + dl*4;

  float cx[NK], cy[NK], cz[NK], cw[NK], ls[NK];
  #pragma unroll
  for (int k = 0; k < NK; ++k) { cx[k]=cy[k]=cz[k]=cw[k]=ls[k]=0.f; }

  #define XLOAD(it) (*(const float4*)(xrow + (it)*(8*ND) + laneoff))
  #define PROCESS(xa)                                                         \
    {                                                                         \
      _Pragma("unroll")                                                       \
      for (int k = 0; k < NK; ++k) {                                          \
        float t = xa.x*vkt[k][0] + xa.y*vkt[k][1]                             \
                + xa.z*vkt[k][2] + xa.w*vkt[k][3];                            \
        t = dpp_add<0xB1>(t);                                                 \
        t = dpp_add<0x4E>(t);                                                 \
        t = dpp_add<0x141>(t);                                                \
        const float p = __expf(t);                                            \
        ls[k] += p;                                                           \
        cx[k] = fmaf(p, xa.x, cx[k]);                                         \
        cy[k] = fmaf(p, xa.y, cy[k]);                                         \
        cz[k] = fmaf(p, xa.z, cz[k]);                                         \
        cw[k] = fmaf(p, xa.w, cw[k]);                                         \
      }                                                                       \
    }

  // ---- stage 1: streaming pass, 4-deep rotating pipeline ----
  {
    float4 b0 = XLOAD(0), b1_ = XLOAD(1), b2_ = XLOAD(2), b3 = XLOAD(3);
    // iterations 0..23 in 6 groups of 4; 25th handled after
    for (int g = 0; g < 6; ++g) {
      const int base = g * 4;
      {
        const float4 cur = b0;
        if (base + 4 < NF/8) b0 = XLOAD(base + 4);
        PROCESS(cur);
      }
      {
        const float4 cur = b1_;
        if (base + 5 < NF/8) b1_ = XLOAD(base + 5);
        PROCESS(cur);
      }
      {
        const float4 cur = b2_;
        if (base + 6 < NF/8) b2_ = XLOAD(base + 6);
        PROCESS(cur);
      }
      {
        const float4 cur = b3;
        if (base + 7 < NF/8) b3 = XLOAD(base + 7);
        PROCESS(cur);
      }
    }
    PROCESS(b0);   // iteration 24
  }
  #undef PROCESS
  #undef XLOAD

  // ---- tail: combine the 8 f-groups (mask 8 via DPP, 16/32 via shfl) ----
  #pragma unroll
  for (int k = 0; k < NK; ++k) {
    ls[k] = dpp_add<0x128>(ls[k]);
    cx[k] = dpp_add<0x128>(cx[k]);
    cy[k] = dpp_add<0x128>(cy[k]);
    cz[k] = dpp_add<0x128>(cz[k]);
    cw[k] = dpp_add<0x128>(cw[k]);
    #pragma unroll
    for (int m = 16; m <= 32; m <<= 1) {
      ls[k] += __shfl_xor(ls[k], m);
      cx[k] += __shfl_xor(cx[k], m);
      cy[k] += __shfl_xor(cy[k], m);
      cz[k] += __shfl_xor(cz[k], m);
      cw[k] += __shfl_xor(cw[k], m);
    }
  }

  const float scale = 0.17677669529663687f;  // 1/sqrt(32)
  if (fg == 0) {
    #pragma unroll
    for (int k = 0; k < NK; ++k) {
      const float inv = scale / ls[k];
      float* p = &ctx_s[wave][k*ND + dl*4];
      p[0] = cx[k]*inv; p[1] = cy[k]*inv; p[2] = cz[k]*inv; p[3] = cw[k]*inv;
    }
  }
  __syncthreads();

  // ---- stage 2: tower 1 (Dense -> BN -> relu); weights from global/L2 ----
  #pragma unroll
  for (int rep = 0; rep < 2; ++rep) {
    const int o = lane + rep*64;
    const int k = o >> 5, h = o & 31;
    const float* wp = W1 + k*(ND*NH1) + h;
    const float* cp = &ctx_s[wave][k*ND];
    float acc = 0.f;
    #pragma unroll
    for (int d = 0; d < ND; ++d) acc = fmaf(cp[d], wp[d*NH1], acc);
    const float a = g1[o] * rsqrtf(v1[o] + BN_EPS);
    const float c = fmaf(b1[o] - m1[o], a, be1[o]);
    h1_s[wave][o] = fmaxf(fmaf(acc, a, c), 0.f);
  }
  __syncthreads();

  // ---- stage 3: tower 2 + gate + output ----
  {
    const int k3 = lane >> 4, j3 = lane & 15;
    const float* wp = W2 + k3*(NH1*NH2) + j3;
    const float* hp = &h1_s[wave][k3*NH1];
    float acc = 0.f;
    #pragma unroll
    for (int h = 0; h < NH1; ++h) acc = fmaf(hp[h], wp[h*NH2], acc);
    const int o = k3*NH2 + j3;
    const float a2 = g2[o] * rsqrtf(v2[o] + BN_EPS);
    const float c2 = fmaf(b2[o] - m2[o], a2, be2[o]);
    const float h2v = fmaxf(fmaf(acc, a2, c2), 0.f);

    // gate from tag embedding (redundant per lane; tag row is L1-hot)
    const float* tp = tag + (size_t)(live ? row : 0) * ND;
    float gs0=0.f, gs1=0.f, gs2=0.f, gs3=0.f;
    #pragma unroll
    for (int d = 0; d < ND; ++d) {
      const float t = tp[d];
      const float4 vv = *(const float4*)(vk + d*NK);
      gs0 = fmaf(t, vv.x, gs0);
      gs1 = fmaf(t, vv.y, gs1);
      gs2 = fmaf(t, vv.z, gs2);
      gs3 = fmaf(t, vv.w, gs3);
    }
    gs0 *= scale; gs1 *= scale; gs2 *= scale; gs3 *= scale;
    const float mx = fmaxf(fmaxf(gs0, gs1), fmaxf(gs2, gs3));
    const float e0 = __expf(gs0-mx), e1 = __expf(gs1-mx),
                e2 = __expf(gs2-mx), e3 = __expf(gs3-mx);
    const float esum = e0 + e1 + e2 + e3;
    const float ek = (k3 == 0) ? e0 : (k3 == 1) ? e1 : (k3 == 2) ? e2 : e3;

    float val = (ek / esum) * h2v;
    val += __shfl_xor(val, 16);
    val += __shfl_xor(val, 32);        // sum over the 4 experts
    if (live && lane < NH2) out[(size_t)row*NH2 + lane] = val;
  }
}

extern "C" void kernel_launch(void* const* d_in, const int* in_sizes, int n_in,
                              void* d_out, int out_size, void* d_ws, size_t ws_size,
                              hipStream_t stream) {
  const float* x   = (const float*)d_in[0];
  const float* tag = (const float*)d_in[1];
  const float* vk  = (const float*)d_in[2];
  const float* W1  = (const float*)d_in[3];
  const float* b1  = (const float*)d_in[4];
  const float* g1  = (const float*)d_in[5];
  const float* be1 = (const float*)d_in[6];
  const float* m1  = (const float*)d_in[7];
  const float* v1  = (const float*)d_in[8];
  const float* W2  = (const float*)d_in[9];
  const float* b2  = (const float*)d_in[10];
  const float* g2  = (const float*)d_in[11];
  const float* be2 = (const float*)d_in[12];
  const float* m2  = (const float*)d_in[13];
  const float* v2  = (const float*)d_in[14];
  float* out = (float*)d_out;

  const int nrows = in_sizes[1] / ND;          // B from tag_embedding
  const int nblocks = (nrows + 3) / 4;         // 4 waves/block, 1 row/wave
  mvke_fused<<<nblocks, 256, 0, stream>>>(x, tag, vk, W1, b1, g1, be1, m1, v1,
                                          W2, b2, g2, be2, m2, v2, out, nrows);
}